// Round 2
// baseline (977.971 us; speedup 1.0000x reference)
//
#include <hip/hip_runtime.h>
#include <hip/hip_bf16.h>

// AudioAttnBlock: GroupNorm -> QKV 1x1 conv -> spatial attention -> out proj -> residual
// B=4, C=512, H=W=64 (N=4096), 32 groups.
// All heavy math in bf16 MFMA (16x16x32), fp32 accumulate. Threshold is bf16-floored.

#define C_DIM 512
#define N_SPA 4096
#define BATCH 4
#define NGRP 32
#define GSZ 16

#define BM 128
#define BN 128
#define BK 32
#define LDT 40  // LDS k-stride (elems), padded 32->40 to break bank-conflict stride

typedef short short8 __attribute__((ext_vector_type(8)));
typedef short short4v __attribute__((ext_vector_type(4)));
typedef float float4v __attribute__((ext_vector_type(4)));

__device__ __forceinline__ short f2b(float f) {
  __hip_bfloat16 h = __float2bfloat16(f);
  return *reinterpret_cast<short*>(&h);
}
__device__ __forceinline__ float b2f(short s) {
  __hip_bfloat16 h;
  *reinterpret_cast<short*>(&h) = s;
  return __bfloat162float(h);
}

// ---------------- weight fp32 -> bf16 convert (4 x 512x512) ----------------
__global__ void wconv_kernel(const float* __restrict__ Wq, const float* __restrict__ Wk,
                             const float* __restrict__ Wv, const float* __restrict__ Wo,
                             short* __restrict__ out) {
  int i = blockIdx.x * 256 + threadIdx.x;  // 0..262143
  out[0 * 262144 + i] = f2b(Wq[i]);
  out[1 * 262144 + i] = f2b(Wk[i]);
  out[2 * 262144 + i] = f2b(Wv[i]);
  out[3 * 262144 + i] = f2b(Wo[i]);
}

// ---------------- GroupNorm: x[B,C,N] fp32 -> h_t[B,N,C] bf16 ----------------
// one block per (b, group): reduce 16ch x 4096 spatial, then normalize+transpose via LDS tile
__global__ void gn_kernel(const float* __restrict__ x, const float* __restrict__ gamma,
                          const float* __restrict__ beta, short* __restrict__ h_t) {
  int b = blockIdx.x >> 5;
  int g = blockIdx.x & 31;
  const float* xg = x + ((size_t)b * C_DIM + g * GSZ) * N_SPA;  // 16 rows of 4096
  int t = threadIdx.x;

  // pass 1: sum / sumsq over 65536 elems (coalesced: consecutive t -> consecutive n)
  float s = 0.f, ss = 0.f;
  for (int e = t; e < GSZ * N_SPA; e += 256) {
    float v = xg[e];
    s += v; ss += v * v;
  }
  __shared__ float red[512];
  red[t] = s; red[256 + t] = ss;
  __syncthreads();
  for (int off = 128; off > 0; off >>= 1) {
    if (t < off) { red[t] += red[t + off]; red[256 + t] += red[256 + t + off]; }
    __syncthreads();
  }
  float mean = red[0] * (1.0f / 65536.0f);
  float var  = red[256] * (1.0f / 65536.0f) - mean * mean;
  float rstd = rsqrtf(var + 1e-6f);

  // pass 2: 16c x 256n tiles; coalesced read, transpose in LDS (pad 257), 32B-chunk writes
  __shared__ float tile[GSZ][257];
  int cl = t & 15, no = t >> 4;
  float ga = gamma[g * GSZ + cl], be = beta[g * GSZ + cl];
  for (int n0 = 0; n0 < N_SPA; n0 += 256) {
    __syncthreads();
    for (int i = 0; i < GSZ; ++i) tile[i][t] = xg[i * N_SPA + n0 + t];
    __syncthreads();
    for (int j = 0; j < 16; ++j) {
      int n = no + j * 16;
      float v = (tile[cl][n] - mean) * rstd * ga + be;
      h_t[((size_t)b * N_SPA + n0 + n) * C_DIM + g * GSZ + cl] = f2b(v);
    }
  }
}

// ---------------- GEMM: C[M,N] = A[M,K] * BT[N,K]^T (+epilogue) ----------------
// EPI 0: bf16 out transposed [N,M], +bias[m]        (q_t, k_t)
// EPI 1: bf16 out normal [M,N], +bias[m]            (v)
// EPI 2: bf16 out normal, *scale                    (attn logits)
// EPI 3: bf16 out transposed, no bias               (o_t = (V P^T)^T)
// EPI 4: fp32 out normal, +bias[m] +resid[M,N]      (final y = x + Wo o + bo)
template <int EPI>
__global__ __launch_bounds__(256) void gemm_bt(
    const short* __restrict__ A, const short* __restrict__ BT, void* __restrict__ Cout,
    const float* __restrict__ bias, const float* __restrict__ resid,
    int M, int N, int K, float scale) {
  __shared__ __align__(16) short lds_a[BM * LDT];
  __shared__ __align__(16) short lds_b[BN * LDT];
  int t = threadIdx.x;
  int m0 = blockIdx.y * BM;
  int n0 = blockIdx.x * BN;
  int w = t >> 6, l = t & 63;
  int wm = (w >> 1) * 64, wn = (w & 1) * 64;
  int lr = l & 15, lk = l >> 4;  // fragment row/col, k-group

  float4v acc[4][4];
#pragma unroll
  for (int i = 0; i < 4; ++i)
#pragma unroll
    for (int j = 0; j < 4; ++j) acc[i][j] = (float4v){0.f, 0.f, 0.f, 0.f};

  int srow = t >> 2;          // 0..63
  int scol = (t & 3) * 8;     // 0,8,16,24

  for (int k0 = 0; k0 < K; k0 += BK) {
    __syncthreads();
    {
      const short* Ap = A + (size_t)(m0 + srow) * K + k0 + scol;
      *(short8*)&lds_a[srow * LDT + scol]        = *(const short8*)Ap;
      *(short8*)&lds_a[(srow + 64) * LDT + scol] = *(const short8*)(Ap + (size_t)64 * K);
      const short* Bp = BT + (size_t)(n0 + srow) * K + k0 + scol;
      *(short8*)&lds_b[srow * LDT + scol]        = *(const short8*)Bp;
      *(short8*)&lds_b[(srow + 64) * LDT + scol] = *(const short8*)(Bp + (size_t)64 * K);
    }
    __syncthreads();
    short8 af[4], bf[4];
#pragma unroll
    for (int i = 0; i < 4; ++i) af[i] = *(const short8*)&lds_a[(wm + i * 16 + lr) * LDT + lk * 8];
#pragma unroll
    for (int i = 0; i < 4; ++i) bf[i] = *(const short8*)&lds_b[(wn + i * 16 + lr) * LDT + lk * 8];
#pragma unroll
    for (int i = 0; i < 4; ++i)
#pragma unroll
      for (int j = 0; j < 4; ++j)
        acc[i][j] = __builtin_amdgcn_mfma_f32_16x16x32_bf16(af[i], bf[j], acc[i][j], 0, 0, 0);
  }

#pragma unroll
  for (int i = 0; i < 4; ++i)
#pragma unroll
    for (int j = 0; j < 4; ++j) {
      int mB = m0 + wm + i * 16 + lk * 4;        // first of 4 consecutive rows
      int nn = n0 + wn + j * 16 + lr;            // column
      if constexpr (EPI == 0 || EPI == 3) {
        short4v v;
#pragma unroll
        for (int r = 0; r < 4; ++r) {
          float f = acc[i][j][r];
          if constexpr (EPI == 0) f += bias[mB + r];
          v[r] = f2b(f);
        }
        *(short4v*)((short*)Cout + (size_t)nn * M + mB) = v;  // transposed store, 8B/lane
      } else if constexpr (EPI == 1 || EPI == 2) {
#pragma unroll
        for (int r = 0; r < 4; ++r) {
          float f = acc[i][j][r];
          if constexpr (EPI == 1) f += bias[mB + r];
          if constexpr (EPI == 2) f *= scale;
          ((short*)Cout)[(size_t)(mB + r) * N + nn] = f2b(f);
        }
      } else {  // EPI 4
#pragma unroll
        for (int r = 0; r < 4; ++r) {
          float f = acc[i][j][r] + bias[mB + r] + resid[(size_t)(mB + r) * N + nn];
          ((float*)Cout)[(size_t)(mB + r) * N + nn] = f;
        }
      }
    }
}

// ---------------- row softmax over 4096 cols, bf16 in-place ----------------
__global__ void softmax_kernel(short* __restrict__ p) {
  int row = blockIdx.x;
  short8* pr = (short8*)(p + (size_t)row * N_SPA);  // 512 vec8
  int t = threadIdx.x;
  short8 a = pr[t * 2], b = pr[t * 2 + 1];
  float v[16];
#pragma unroll
  for (int j = 0; j < 8; ++j) { v[j] = b2f(a[j]); v[8 + j] = b2f(b[j]); }
  float mx = v[0];
#pragma unroll
  for (int j = 1; j < 16; ++j) mx = fmaxf(mx, v[j]);
  __shared__ float red[256];
  red[t] = mx; __syncthreads();
  for (int off = 128; off > 0; off >>= 1) {
    if (t < off) red[t] = fmaxf(red[t], red[t + off]);
    __syncthreads();
  }
  mx = red[0];
  __syncthreads();
  float s = 0.f;
#pragma unroll
  for (int j = 0; j < 16; ++j) { v[j] = __expf(v[j] - mx); s += v[j]; }
  red[t] = s; __syncthreads();
  for (int off = 128; off > 0; off >>= 1) {
    if (t < off) red[t] += red[t + off];
    __syncthreads();
  }
  float inv = 1.0f / red[0];
  short8 oa, ob;
#pragma unroll
  for (int j = 0; j < 8; ++j) { oa[j] = f2b(v[j] * inv); ob[j] = f2b(v[8 + j] * inv); }
  pr[t * 2] = oa; pr[t * 2 + 1] = ob;
}

extern "C" void kernel_launch(void* const* d_in, const int* in_sizes, int n_in,
                              void* d_out, int out_size, void* d_ws, size_t ws_size,
                              hipStream_t stream) {
  const float* x     = (const float*)d_in[0];
  const float* gamma = (const float*)d_in[1];
  const float* beta  = (const float*)d_in[2];
  const float* Wq = (const float*)d_in[3];  const float* bq = (const float*)d_in[4];
  const float* Wk = (const float*)d_in[5];  const float* bk = (const float*)d_in[6];
  const float* Wv = (const float*)d_in[7];  const float* bv = (const float*)d_in[8];
  const float* Wo = (const float*)d_in[9];  const float* bo = (const float*)d_in[10];
  float* out = (float*)d_out;

  // workspace carve-up (bf16 elements). total ~66 MB.
  short* Wb  = (short*)d_ws;                                  // 4 x 262144
  short* h_t = Wb + 4 * 262144;                               // [B][N][C]
  short* q_t = h_t + (size_t)BATCH * N_SPA * C_DIM;           // [N][C] per batch
  short* k_t = q_t + (size_t)N_SPA * C_DIM;
  short* v_  = k_t + (size_t)N_SPA * C_DIM;                   // [C][N] per batch
  short* p   = v_  + (size_t)N_SPA * C_DIM;                   // [N][N] per batch
  short* o_t = p   + (size_t)N_SPA * N_SPA;                   // [N][C] per batch

  wconv_kernel<<<1024, 256, 0, stream>>>(Wq, Wk, Wv, Wo, Wb);
  gn_kernel<<<BATCH * NGRP, 256, 0, stream>>>(x, gamma, beta, h_t);

  const float scale = 0.04419417382415922f;  // 512^-0.5
  dim3 gproj(N_SPA / BN, C_DIM / BM);   // 32 x 4
  dim3 gattn(N_SPA / BN, N_SPA / BM);   // 32 x 32

  for (int b = 0; b < BATCH; ++b) {
    const short* hb = h_t + (size_t)b * N_SPA * C_DIM;
    const float* xb = x + (size_t)b * C_DIM * N_SPA;
    float* yb = out + (size_t)b * C_DIM * N_SPA;
    // q_t[n][c], k_t[n][c] (transposed store), v[c][n]
    gemm_bt<0><<<gproj, 256, 0, stream>>>(Wb + 0 * 262144, hb, q_t, bq, nullptr, C_DIM, N_SPA, C_DIM, 0.f);
    gemm_bt<0><<<gproj, 256, 0, stream>>>(Wb + 1 * 262144, hb, k_t, bk, nullptr, C_DIM, N_SPA, C_DIM, 0.f);
    gemm_bt<1><<<gproj, 256, 0, stream>>>(Wb + 2 * 262144, hb, v_, bv, nullptr, C_DIM, N_SPA, C_DIM, 0.f);
    // logits[i][j] = scale * sum_c q_t[i][c] k_t[j][c]
    gemm_bt<2><<<gattn, 256, 0, stream>>>(q_t, k_t, p, nullptr, nullptr, N_SPA, N_SPA, C_DIM, scale);
    softmax_kernel<<<N_SPA, 256, 0, stream>>>(p);
    // o_t[i][c] = sum_j v[c][j] p[i][j]  (transposed store of V P^T)
    gemm_bt<3><<<gproj, 256, 0, stream>>>(v_, p, o_t, nullptr, nullptr, C_DIM, N_SPA, N_SPA, 0.f);
    // y[c][n] = x[c][n] + bo[c] + sum_k Wo[c][k] o_t[n][k]
    gemm_bt<4><<<gproj, 256, 0, stream>>>(Wb + 3 * 262144, o_t, yb, bo, xb, C_DIM, N_SPA, C_DIM, 0.f);
  }
}

// Round 3
// 695.058 us; speedup vs baseline: 1.4070x; 1.4070x over previous
//
#include <hip/hip_runtime.h>
#include <hip/hip_bf16.h>

// AudioAttnBlock: GroupNorm -> QKV 1x1 conv -> spatial attention -> out proj -> residual
// B=4, C=512, N=4096 (64x64), 32 groups. bf16 MFMA 16x16x32, fp32 accumulate.
// R3: gn split into 3 phases (was 130us latency-bound at 128 blocks);
//     GEMM staging via global_load_lds width=16 (m97 structure, linear LDS);
//     projections batched over all 4 batches (N=16384) for full-grid occupancy.

#define C_DIM 512
#define N_SPA 4096
#define BATCH 4
#define NALL 16384  // BATCH * N_SPA

#define BM 128
#define BN 128
#define BK 32

typedef short short8 __attribute__((ext_vector_type(8)));
typedef short short4v __attribute__((ext_vector_type(4)));
typedef float float4v __attribute__((ext_vector_type(4)));

__device__ __forceinline__ short f2b(float f) {
  __hip_bfloat16 h = __float2bfloat16(f);
  return *reinterpret_cast<short*>(&h);
}
__device__ __forceinline__ float b2f(short s) {
  __hip_bfloat16 h;
  *reinterpret_cast<short*>(&h) = s;
  return __bfloat162float(h);
}

typedef __attribute__((address_space(1))) const void gvoid_t;
typedef __attribute__((address_space(3))) void lvoid_t;
__device__ __forceinline__ void gload16(const void* g, void* l) {
  // async global->LDS, 16B/lane; LDS dest = wave-uniform base + lane*16
  __builtin_amdgcn_global_load_lds((gvoid_t*)g, (lvoid_t*)l, 16, 0, 0);
}

// ---------------- weight fp32 -> bf16 convert (4 x 512x512) ----------------
__global__ void wconv_kernel(const float* __restrict__ Wq, const float* __restrict__ Wk,
                             const float* __restrict__ Wv, const float* __restrict__ Wo,
                             short* __restrict__ out) {
  int i = blockIdx.x * 256 + threadIdx.x;
  out[0 * 262144 + i] = f2b(Wq[i]);
  out[1 * 262144 + i] = f2b(Wk[i]);
  out[2 * 262144 + i] = f2b(Wv[i]);
  out[3 * 262144 + i] = f2b(Wo[i]);
}

// ---------------- GroupNorm phase 1: partial sums ----------------
// grid 4096 = 128 groups x 32 splits; each block reduces 2048 contiguous floats
__global__ void gn_part(const float* __restrict__ x, float2* __restrict__ partials) {
  int grp = blockIdx.x >> 5, split = blockIdx.x & 31;
  const float4* xg = (const float4*)(x + (size_t)grp * 65536 + split * 2048);
  int t = threadIdx.x;
  float4 a = xg[t], b4 = xg[256 + t];
  float s = a.x + a.y + a.z + a.w + b4.x + b4.y + b4.z + b4.w;
  float ss = a.x * a.x + a.y * a.y + a.z * a.z + a.w * a.w +
             b4.x * b4.x + b4.y * b4.y + b4.z * b4.z + b4.w * b4.w;
  __shared__ float red[512];
  red[t] = s; red[256 + t] = ss;
  __syncthreads();
  for (int off = 128; off > 0; off >>= 1) {
    if (t < off) { red[t] += red[t + off]; red[256 + t] += red[256 + t + off]; }
    __syncthreads();
  }
  if (t == 0) partials[blockIdx.x] = make_float2(red[0], red[256]);
}

// ---------------- GroupNorm phase 2: normalize + transpose ----------------
// grid 2048 = 128 groups x 16 segments of 256 n; each block reduces its group's
// 32 partials redundantly (256B, cached), then writes h_t[B*N][C] bf16.
__global__ void gn_norm(const float* __restrict__ x, const float* __restrict__ gamma,
                        const float* __restrict__ beta, const float2* __restrict__ partials,
                        short* __restrict__ h_t) {
  int bid = blockIdx.x;
  int grp = bid >> 4, seg = bid & 15;
  int b = grp >> 5, g = grp & 31;
  float s = 0.f, ss = 0.f;
  for (int j = 0; j < 32; ++j) { float2 p2 = partials[grp * 32 + j]; s += p2.x; ss += p2.y; }
  float mean = s * (1.0f / 65536.0f);
  float rstd = rsqrtf(ss * (1.0f / 65536.0f) - mean * mean + 1e-6f);

  const float* xg = x + (size_t)grp * 65536 + seg * 256;  // channel row stride N_SPA
  __shared__ float tile[16][257];
  int t = threadIdx.x;
#pragma unroll
  for (int i = 0; i < 16; ++i) tile[i][t] = xg[(size_t)i * N_SPA + t];
  __syncthreads();

  int c8 = (t & 1) * 8, ci = g * 16 + c8;
  float ga[8], be[8];
#pragma unroll
  for (int j = 0; j < 8; ++j) { ga[j] = gamma[ci + j]; be[j] = beta[ci + j]; }
#pragma unroll
  for (int pass = 0; pass < 2; ++pass) {
    int nl = (t >> 1) + pass * 128;
    short8 o;
#pragma unroll
    for (int j = 0; j < 8; ++j) {
      float v = (tile[c8 + j][nl] - mean) * rstd * ga[j] + be[j];
      o[j] = f2b(v);
    }
    *(short8*)&h_t[((size_t)b * N_SPA + seg * 256 + nl) * C_DIM + ci] = o;
  }
}

// ---------------- GEMM: C[M,N] = A[M,K] * BT[N,K]^T (+epilogue) ----------------
// m97 structure: global_load_lds width=16 into LINEAR LDS [128][32] (no pad —
// dest is wave-uniform base + lane*16; fragment reads are contiguous 1KB/wave,
// conflict-free). 2 barriers per K-step.
// EPI 0: bf16 out transposed [n][m], +bias[m]        (q_t, k_t)
// EPI 1: bf16 out normal [m][n], +bias[m]            (v)
// EPI 2: bf16 out normal, *scale                     (attn logits)
// EPI 3: bf16 out transposed, no bias                (o_t = (V P^T)^T)
// EPI 4: fp32 out, +bias[m] +resid, batched [B][C][N] decomposition of nn
template <int EPI>
__global__ __launch_bounds__(256) void gemm_bt(
    const short* __restrict__ A, const short* __restrict__ BT, void* __restrict__ Cout,
    const float* __restrict__ bias, const float* __restrict__ resid,
    int M, int N, int K, int lda, int ldb, int ldc, float scale) {
  __shared__ __align__(16) short lds_a[BM * BK];
  __shared__ __align__(16) short lds_b[BN * BK];
  int t = threadIdx.x;
  int m0 = blockIdx.y * BM;
  int n0 = blockIdx.x * BN;
  int w = t >> 6, l = t & 63;
  int wm = (w >> 1) * 64, wn = (w & 1) * 64;
  int lr = l & 15, lk = l >> 4;

  // staging: wave w covers rows w*16..w*16+15 (and +64); lane l -> row w*16+(l>>2), col (l&3)*8
  int sr = l >> 2, scol = (l & 3) * 8;
  const short* ga0 = A + (size_t)(m0 + w * 16 + sr) * lda + scol;
  const short* ga1 = ga0 + (size_t)64 * lda;
  const short* gb0 = BT + (size_t)(n0 + w * 16 + sr) * ldb + scol;
  const short* gb1 = gb0 + (size_t)64 * ldb;
  short* la0 = &lds_a[w * 16 * BK];
  short* la1 = &lds_a[(64 + w * 16) * BK];
  short* lb0 = &lds_b[w * 16 * BK];
  short* lb1 = &lds_b[(64 + w * 16) * BK];

  float4v acc[4][4];
#pragma unroll
  for (int i = 0; i < 4; ++i)
#pragma unroll
    for (int j = 0; j < 4; ++j) acc[i][j] = (float4v){0.f, 0.f, 0.f, 0.f};

  for (int k0 = 0; k0 < K; k0 += BK) {
    __syncthreads();
    gload16(ga0, la0); gload16(ga1, la1);
    gload16(gb0, lb0); gload16(gb1, lb1);
    ga0 += BK; ga1 += BK; gb0 += BK; gb1 += BK;
    __syncthreads();  // compiler drains vmcnt before barrier
    short8 af[4], bf[4];
#pragma unroll
    for (int i = 0; i < 4; ++i) af[i] = *(const short8*)&lds_a[(wm + i * 16 + lr) * BK + lk * 8];
#pragma unroll
    for (int i = 0; i < 4; ++i) bf[i] = *(const short8*)&lds_b[(wn + i * 16 + lr) * BK + lk * 8];
#pragma unroll
    for (int i = 0; i < 4; ++i)
#pragma unroll
      for (int j = 0; j < 4; ++j)
        acc[i][j] = __builtin_amdgcn_mfma_f32_16x16x32_bf16(af[i], bf[j], acc[i][j], 0, 0, 0);
  }

#pragma unroll
  for (int i = 0; i < 4; ++i)
#pragma unroll
    for (int j = 0; j < 4; ++j) {
      int mB = m0 + wm + i * 16 + lk * 4;   // first of 4 consecutive out-rows
      int nn = n0 + wn + j * 16 + lr;       // out-column
      if constexpr (EPI == 0 || EPI == 3) {
        short4v v;
#pragma unroll
        for (int r = 0; r < 4; ++r) {
          float f = acc[i][j][r];
          if constexpr (EPI == 0) f += bias[mB + r];
          v[r] = f2b(f);
        }
        *(short4v*)((short*)Cout + (size_t)nn * ldc + mB) = v;
      } else if constexpr (EPI == 1 || EPI == 2) {
#pragma unroll
        for (int r = 0; r < 4; ++r) {
          float f = acc[i][j][r];
          if constexpr (EPI == 1) f += bias[mB + r];
          if constexpr (EPI == 2) f *= scale;
          ((short*)Cout)[(size_t)(mB + r) * ldc + nn] = f2b(f);
        }
      } else {  // EPI 4: y[b][c][n] = acc + bias[c] + x[b][c][n]
        int bb = nn >> 12, n = nn & 4095;
        size_t base = ((size_t)bb * C_DIM + mB) * N_SPA + n;
#pragma unroll
        for (int r = 0; r < 4; ++r) {
          float f = acc[i][j][r] + bias[mB + r] + resid[base + (size_t)r * N_SPA];
          ((float*)Cout)[base + (size_t)r * N_SPA] = f;
        }
      }
    }
}

// ---------------- row softmax over 4096 cols, bf16 in-place ----------------
__global__ void softmax_kernel(short* __restrict__ p) {
  int row = blockIdx.x;
  short8* pr = (short8*)(p + (size_t)row * N_SPA);
  int t = threadIdx.x;
  short8 a = pr[t * 2], b = pr[t * 2 + 1];
  float v[16];
#pragma unroll
  for (int j = 0; j < 8; ++j) { v[j] = b2f(a[j]); v[8 + j] = b2f(b[j]); }
  float mx = v[0];
#pragma unroll
  for (int j = 1; j < 16; ++j) mx = fmaxf(mx, v[j]);
  __shared__ float red[256];
  red[t] = mx; __syncthreads();
  for (int off = 128; off > 0; off >>= 1) {
    if (t < off) red[t] = fmaxf(red[t], red[t + off]);
    __syncthreads();
  }
  mx = red[0];
  __syncthreads();
  float s = 0.f;
#pragma unroll
  for (int j = 0; j < 16; ++j) { v[j] = __expf(v[j] - mx); s += v[j]; }
  red[t] = s; __syncthreads();
  for (int off = 128; off > 0; off >>= 1) {
    if (t < off) red[t] += red[t + off];
    __syncthreads();
  }
  float inv = 1.0f / red[0];
  short8 oa, ob;
#pragma unroll
  for (int j = 0; j < 8; ++j) { oa[j] = f2b(v[j] * inv); ob[j] = f2b(v[8 + j] * inv); }
  pr[t * 2] = oa; pr[t * 2 + 1] = ob;
}

extern "C" void kernel_launch(void* const* d_in, const int* in_sizes, int n_in,
                              void* d_out, int out_size, void* d_ws, size_t ws_size,
                              hipStream_t stream) {
  const float* x     = (const float*)d_in[0];
  const float* gamma = (const float*)d_in[1];
  const float* beta  = (const float*)d_in[2];
  const float* Wq = (const float*)d_in[3];  const float* bq = (const float*)d_in[4];
  const float* Wk = (const float*)d_in[5];  const float* bk = (const float*)d_in[6];
  const float* Wv = (const float*)d_in[7];  const float* bv = (const float*)d_in[8];
  const float* Wo = (const float*)d_in[9];  const float* bo = (const float*)d_in[10];
  float* out = (float*)d_out;

  // workspace (shorts). h_t aliased as o_t after projections (dead then). ~103 MB.
  short* Wb  = (short*)d_ws;                              // 4 x 262144
  short* h_t = Wb + 4 * 262144;                           // [B*N][C] (later: o_t)
  short* q_t = h_t + (size_t)NALL * C_DIM;                // [B*N][C]
  short* k_t = q_t + (size_t)NALL * C_DIM;                // [B*N][C]
  short* v_  = k_t + (size_t)NALL * C_DIM;                // [C][B*N]
  short* p   = v_  + (size_t)NALL * C_DIM;                // [N][N] one batch at a time
  float2* partials = (float2*)(p + (size_t)N_SPA * N_SPA);  // 4096 float2
  short* o_t = h_t;

  wconv_kernel<<<1024, 256, 0, stream>>>(Wq, Wk, Wv, Wo, Wb);
  gn_part<<<BATCH * 32 * 32, 256, 0, stream>>>(x, partials);
  gn_norm<<<BATCH * 32 * 16, 256, 0, stream>>>(x, gamma, beta, partials, h_t);

  const float scale = 0.04419417382415922f;  // 512^-0.5
  dim3 gproj(NALL / BN, C_DIM / BM);    // 128 x 4 = 512 blocks
  dim3 gattn(N_SPA / BN, N_SPA / BM);   // 32 x 32
  dim3 gpv(N_SPA / BN, C_DIM / BM);     // 32 x 4

  // batched projections: q_t/k_t [B*N][C] (transposed store), v [C][B*N]
  gemm_bt<0><<<gproj, 256, 0, stream>>>(Wb + 0 * 262144, h_t, q_t, bq, nullptr,
                                        C_DIM, NALL, C_DIM, C_DIM, C_DIM, C_DIM, 0.f);
  gemm_bt<0><<<gproj, 256, 0, stream>>>(Wb + 1 * 262144, h_t, k_t, bk, nullptr,
                                        C_DIM, NALL, C_DIM, C_DIM, C_DIM, C_DIM, 0.f);
  gemm_bt<1><<<gproj, 256, 0, stream>>>(Wb + 2 * 262144, h_t, v_, bv, nullptr,
                                        C_DIM, NALL, C_DIM, C_DIM, C_DIM, NALL, 0.f);

  for (int b = 0; b < BATCH; ++b) {
    const short* qb = q_t + (size_t)b * N_SPA * C_DIM;
    const short* kb = k_t + (size_t)b * N_SPA * C_DIM;
    const short* vb = v_ + (size_t)b * N_SPA;      // [C] rows, stride NALL
    short* ob = o_t + (size_t)b * N_SPA * C_DIM;   // overwrites h_t[b] (dead)
    // logits[i][j] = scale * sum_c q_t[i][c] k_t[j][c]
    gemm_bt<2><<<gattn, 256, 0, stream>>>(qb, kb, p, nullptr, nullptr,
                                          N_SPA, N_SPA, C_DIM, C_DIM, C_DIM, N_SPA, scale);
    softmax_kernel<<<N_SPA, 256, 0, stream>>>(p);
    // o_t[i][c] = sum_j v[c][j] p[i][j]
    gemm_bt<3><<<gpv, 256, 0, stream>>>(vb, p, ob, nullptr, nullptr,
                                        C_DIM, N_SPA, N_SPA, NALL, N_SPA, C_DIM, 0.f);
  }
  // y[b][c][n] = x + bo[c] + sum_k Wo[c][k] o_t[b*N+n][k]
  gemm_bt<4><<<gproj, 256, 0, stream>>>(Wb + 3 * 262144, o_t, out, bo, x,
                                        C_DIM, NALL, C_DIM, C_DIM, C_DIM, 0, 0.f);
}

// Round 4
// 523.200 us; speedup vs baseline: 1.8692x; 1.3285x over previous
//
#include <hip/hip_runtime.h>
#include <hip/hip_bf16.h>

// AudioAttnBlock: GroupNorm -> QKV 1x1 conv -> spatial attention -> out proj -> residual
// B=4, C=512, N=4096 (64x64), 32 groups. bf16 MFMA 16x16x32, fp32 accumulate.
// R4: PV GEMM was 4x88us at 5% occupancy (128 blocks, K=4096). Reformulated as
//     P*V with split-K=4 (grid 4x32x4 = 512 blocks, K=1024 each) writing fp32
//     partials + vectorized reduce. Everything else unchanged from R3.

#define C_DIM 512
#define N_SPA 4096
#define BATCH 4
#define NALL 16384  // BATCH * N_SPA

#define BM 128
#define BN 128
#define BK 32

typedef short short8 __attribute__((ext_vector_type(8)));
typedef short short4v __attribute__((ext_vector_type(4)));
typedef float float4v __attribute__((ext_vector_type(4)));

__device__ __forceinline__ short f2b(float f) {
  __hip_bfloat16 h = __float2bfloat16(f);
  return *reinterpret_cast<short*>(&h);
}
__device__ __forceinline__ float b2f(short s) {
  __hip_bfloat16 h;
  *reinterpret_cast<short*>(&h) = s;
  return __bfloat162float(h);
}

typedef __attribute__((address_space(1))) const void gvoid_t;
typedef __attribute__((address_space(3))) void lvoid_t;
__device__ __forceinline__ void gload16(const void* g, void* l) {
  // async global->LDS, 16B/lane; LDS dest = wave-uniform base + lane*16
  __builtin_amdgcn_global_load_lds((gvoid_t*)g, (lvoid_t*)l, 16, 0, 0);
}

// ---------------- weight fp32 -> bf16 convert (4 x 512x512) ----------------
__global__ void wconv_kernel(const float* __restrict__ Wq, const float* __restrict__ Wk,
                             const float* __restrict__ Wv, const float* __restrict__ Wo,
                             short* __restrict__ out) {
  int i = blockIdx.x * 256 + threadIdx.x;
  out[0 * 262144 + i] = f2b(Wq[i]);
  out[1 * 262144 + i] = f2b(Wk[i]);
  out[2 * 262144 + i] = f2b(Wv[i]);
  out[3 * 262144 + i] = f2b(Wo[i]);
}

// ---------------- GroupNorm phase 1: partial sums ----------------
__global__ void gn_part(const float* __restrict__ x, float2* __restrict__ partials) {
  int grp = blockIdx.x >> 5, split = blockIdx.x & 31;
  const float4* xg = (const float4*)(x + (size_t)grp * 65536 + split * 2048);
  int t = threadIdx.x;
  float4 a = xg[t], b4 = xg[256 + t];
  float s = a.x + a.y + a.z + a.w + b4.x + b4.y + b4.z + b4.w;
  float ss = a.x * a.x + a.y * a.y + a.z * a.z + a.w * a.w +
             b4.x * b4.x + b4.y * b4.y + b4.z * b4.z + b4.w * b4.w;
  __shared__ float red[512];
  red[t] = s; red[256 + t] = ss;
  __syncthreads();
  for (int off = 128; off > 0; off >>= 1) {
    if (t < off) { red[t] += red[t + off]; red[256 + t] += red[256 + t + off]; }
    __syncthreads();
  }
  if (t == 0) partials[blockIdx.x] = make_float2(red[0], red[256]);
}

// ---------------- GroupNorm phase 2: normalize + transpose ----------------
__global__ void gn_norm(const float* __restrict__ x, const float* __restrict__ gamma,
                        const float* __restrict__ beta, const float2* __restrict__ partials,
                        short* __restrict__ h_t) {
  int bid = blockIdx.x;
  int grp = bid >> 4, seg = bid & 15;
  int b = grp >> 5, g = grp & 31;
  float s = 0.f, ss = 0.f;
  for (int j = 0; j < 32; ++j) { float2 p2 = partials[grp * 32 + j]; s += p2.x; ss += p2.y; }
  float mean = s * (1.0f / 65536.0f);
  float rstd = rsqrtf(ss * (1.0f / 65536.0f) - mean * mean + 1e-6f);

  const float* xg = x + (size_t)grp * 65536 + seg * 256;
  __shared__ float tile[16][257];
  int t = threadIdx.x;
#pragma unroll
  for (int i = 0; i < 16; ++i) tile[i][t] = xg[(size_t)i * N_SPA + t];
  __syncthreads();

  int c8 = (t & 1) * 8, ci = g * 16 + c8;
  float ga[8], be[8];
#pragma unroll
  for (int j = 0; j < 8; ++j) { ga[j] = gamma[ci + j]; be[j] = beta[ci + j]; }
#pragma unroll
  for (int pass = 0; pass < 2; ++pass) {
    int nl = (t >> 1) + pass * 128;
    short8 o;
#pragma unroll
    for (int j = 0; j < 8; ++j) {
      float v = (tile[c8 + j][nl] - mean) * rstd * ga[j] + be[j];
      o[j] = f2b(v);
    }
    *(short8*)&h_t[((size_t)b * N_SPA + seg * 256 + nl) * C_DIM + ci] = o;
  }
}

// ---------------- GEMM: C[M,N] = A[M,K(+kbase)] * BT[N,K(+kbase)]^T ----------------
// blockIdx.z selects a K-split of length K (kbase = z*K).
// EPI 0: bf16 out transposed [n][m], +bias[m]        (q_t, k_t)
// EPI 1: bf16 out normal [m][n], +bias[m]            (v)
// EPI 2: bf16 out normal, *scale                     (attn logits)
// EPI 4: fp32 out, +bias[m] +resid, batched [B][C][N] decomposition of nn
// EPI 5: fp32 partial out at part + z*M*ldc          (split-K PV)
template <int EPI>
__global__ __launch_bounds__(256) void gemm_bt(
    const short* __restrict__ A, const short* __restrict__ BT, void* __restrict__ Cout,
    const float* __restrict__ bias, const float* __restrict__ resid,
    int M, int N, int K, int lda, int ldb, int ldc, float scale) {
  __shared__ __align__(16) short lds_a[BM * BK];
  __shared__ __align__(16) short lds_b[BN * BK];
  int t = threadIdx.x;
  int m0 = blockIdx.y * BM;
  int n0 = blockIdx.x * BN;
  int kbase = blockIdx.z * K;
  int w = t >> 6, l = t & 63;
  int wm = (w >> 1) * 64, wn = (w & 1) * 64;
  int lr = l & 15, lk = l >> 4;

  // staging: wave w covers rows w*16..w*16+15 (and +64); lane l -> row w*16+(l>>2), col (l&3)*8
  int sr = l >> 2, scol = (l & 3) * 8;
  const short* ga0 = A + (size_t)(m0 + w * 16 + sr) * lda + kbase + scol;
  const short* ga1 = ga0 + (size_t)64 * lda;
  const short* gb0 = BT + (size_t)(n0 + w * 16 + sr) * ldb + kbase + scol;
  const short* gb1 = gb0 + (size_t)64 * ldb;
  short* la0 = &lds_a[w * 16 * BK];
  short* la1 = &lds_a[(64 + w * 16) * BK];
  short* lb0 = &lds_b[w * 16 * BK];
  short* lb1 = &lds_b[(64 + w * 16) * BK];

  float4v acc[4][4];
#pragma unroll
  for (int i = 0; i < 4; ++i)
#pragma unroll
    for (int j = 0; j < 4; ++j) acc[i][j] = (float4v){0.f, 0.f, 0.f, 0.f};

  for (int k0 = 0; k0 < K; k0 += BK) {
    __syncthreads();
    gload16(ga0, la0); gload16(ga1, la1);
    gload16(gb0, lb0); gload16(gb1, lb1);
    ga0 += BK; ga1 += BK; gb0 += BK; gb1 += BK;
    __syncthreads();
    short8 af[4], bf[4];
#pragma unroll
    for (int i = 0; i < 4; ++i) af[i] = *(const short8*)&lds_a[(wm + i * 16 + lr) * BK + lk * 8];
#pragma unroll
    for (int i = 0; i < 4; ++i) bf[i] = *(const short8*)&lds_b[(wn + i * 16 + lr) * BK + lk * 8];
#pragma unroll
    for (int i = 0; i < 4; ++i)
#pragma unroll
      for (int j = 0; j < 4; ++j)
        acc[i][j] = __builtin_amdgcn_mfma_f32_16x16x32_bf16(af[i], bf[j], acc[i][j], 0, 0, 0);
  }

#pragma unroll
  for (int i = 0; i < 4; ++i)
#pragma unroll
    for (int j = 0; j < 4; ++j) {
      int mB = m0 + wm + i * 16 + lk * 4;   // first of 4 consecutive out-rows
      int nn = n0 + wn + j * 16 + lr;       // out-column
      if constexpr (EPI == 0) {
        short4v v;
#pragma unroll
        for (int r = 0; r < 4; ++r) v[r] = f2b(acc[i][j][r] + bias[mB + r]);
        *(short4v*)((short*)Cout + (size_t)nn * ldc + mB) = v;
      } else if constexpr (EPI == 1 || EPI == 2) {
#pragma unroll
        for (int r = 0; r < 4; ++r) {
          float f = acc[i][j][r];
          if constexpr (EPI == 1) f += bias[mB + r];
          if constexpr (EPI == 2) f *= scale;
          ((short*)Cout)[(size_t)(mB + r) * ldc + nn] = f2b(f);
        }
      } else if constexpr (EPI == 4) {  // y[b][c][n] = acc + bias[c] + x[b][c][n]
        int bb = nn >> 12, n = nn & 4095;
        size_t base = ((size_t)bb * C_DIM + mB) * N_SPA + n;
#pragma unroll
        for (int r = 0; r < 4; ++r) {
          float f = acc[i][j][r] + bias[mB + r] + resid[base + (size_t)r * N_SPA];
          ((float*)Cout)[base + (size_t)r * N_SPA] = f;
        }
      } else {  // EPI 5: fp32 partial, buffer z
        float* po = (float*)Cout + (size_t)blockIdx.z * M * ldc;
#pragma unroll
        for (int r = 0; r < 4; ++r) po[(size_t)(mB + r) * ldc + nn] = acc[i][j][r];
      }
    }
}

// ---------------- split-K reduce: o_t[n][c] = bf16(sum_s part[s][n][c]) ----------------
__global__ void pv_reduce(const float* __restrict__ part, short* __restrict__ o) {
  int idx = (blockIdx.x * 256 + threadIdx.x) * 4;
  float4 s0 = *(const float4*)(part + idx);
  float4 s1 = *(const float4*)(part + 2097152 + idx);
  float4 s2 = *(const float4*)(part + 2 * 2097152 + idx);
  float4 s3 = *(const float4*)(part + 3 * 2097152 + idx);
  short4v v;
  v[0] = f2b(s0.x + s1.x + s2.x + s3.x);
  v[1] = f2b(s0.y + s1.y + s2.y + s3.y);
  v[2] = f2b(s0.z + s1.z + s2.z + s3.z);
  v[3] = f2b(s0.w + s1.w + s2.w + s3.w);
  *(short4v*)(o + idx) = v;
}

// ---------------- row softmax over 4096 cols, bf16 in-place ----------------
__global__ void softmax_kernel(short* __restrict__ p) {
  int row = blockIdx.x;
  short8* pr = (short8*)(p + (size_t)row * N_SPA);
  int t = threadIdx.x;
  short8 a = pr[t * 2], b = pr[t * 2 + 1];
  float v[16];
#pragma unroll
  for (int j = 0; j < 8; ++j) { v[j] = b2f(a[j]); v[8 + j] = b2f(b[j]); }
  float mx = v[0];
#pragma unroll
  for (int j = 1; j < 16; ++j) mx = fmaxf(mx, v[j]);
  __shared__ float red[256];
  red[t] = mx; __syncthreads();
  for (int off = 128; off > 0; off >>= 1) {
    if (t < off) red[t] = fmaxf(red[t], red[t + off]);
    __syncthreads();
  }
  mx = red[0];
  __syncthreads();
  float s = 0.f;
#pragma unroll
  for (int j = 0; j < 16; ++j) { v[j] = __expf(v[j] - mx); s += v[j]; }
  red[t] = s; __syncthreads();
  for (int off = 128; off > 0; off >>= 1) {
    if (t < off) red[t] += red[t + off];
    __syncthreads();
  }
  float inv = 1.0f / red[0];
  short8 oa, ob;
#pragma unroll
  for (int j = 0; j < 8; ++j) { oa[j] = f2b(v[j] * inv); ob[j] = f2b(v[8 + j] * inv); }
  pr[t * 2] = oa; pr[t * 2 + 1] = ob;
}

extern "C" void kernel_launch(void* const* d_in, const int* in_sizes, int n_in,
                              void* d_out, int out_size, void* d_ws, size_t ws_size,
                              hipStream_t stream) {
  const float* x     = (const float*)d_in[0];
  const float* gamma = (const float*)d_in[1];
  const float* beta  = (const float*)d_in[2];
  const float* Wq = (const float*)d_in[3];  const float* bq = (const float*)d_in[4];
  const float* Wk = (const float*)d_in[5];  const float* bk = (const float*)d_in[6];
  const float* Wv = (const float*)d_in[7];  const float* bv = (const float*)d_in[8];
  const float* Wo = (const float*)d_in[9];  const float* bo = (const float*)d_in[10];
  float* out = (float*)d_out;

  // workspace (shorts unless noted). ~138 MB total.
  short* Wb  = (short*)d_ws;                              // 4 x 262144
  short* h_t = Wb + 4 * 262144;                           // [B*N][C] (later: o_t)
  short* q_t = h_t + (size_t)NALL * C_DIM;                // [B*N][C]
  short* k_t = q_t + (size_t)NALL * C_DIM;                // [B*N][C]
  short* v_  = k_t + (size_t)NALL * C_DIM;                // [C][B*N]
  short* p   = v_  + (size_t)NALL * C_DIM;                // [N][N] one batch at a time
  float* part = (float*)(p + (size_t)N_SPA * N_SPA);      // 4 x [N][C] fp32 split-K partials
  float2* partials = (float2*)(part + 4 * (size_t)N_SPA * C_DIM);  // 4096 float2
  short* o_t = h_t;

  wconv_kernel<<<1024, 256, 0, stream>>>(Wq, Wk, Wv, Wo, Wb);
  gn_part<<<BATCH * 32 * 32, 256, 0, stream>>>(x, partials);
  gn_norm<<<BATCH * 32 * 16, 256, 0, stream>>>(x, gamma, beta, partials, h_t);

  const float scale = 0.04419417382415922f;  // 512^-0.5
  dim3 gproj(NALL / BN, C_DIM / BM);        // 128 x 4 = 512 blocks
  dim3 gattn(N_SPA / BN, N_SPA / BM);       // 32 x 32
  dim3 gpv(C_DIM / BN, N_SPA / BM, 4);      // 4 x 32 x 4 splits = 512 blocks

  // batched projections: q_t/k_t [B*N][C] (transposed store), v [C][B*N]
  gemm_bt<0><<<gproj, 256, 0, stream>>>(Wb + 0 * 262144, h_t, q_t, bq, nullptr,
                                        C_DIM, NALL, C_DIM, C_DIM, C_DIM, C_DIM, 0.f);
  gemm_bt<0><<<gproj, 256, 0, stream>>>(Wb + 1 * 262144, h_t, k_t, bk, nullptr,
                                        C_DIM, NALL, C_DIM, C_DIM, C_DIM, C_DIM, 0.f);
  gemm_bt<1><<<gproj, 256, 0, stream>>>(Wb + 2 * 262144, h_t, v_, bv, nullptr,
                                        C_DIM, NALL, C_DIM, C_DIM, C_DIM, NALL, 0.f);

  for (int b = 0; b < BATCH; ++b) {
    const short* qb = q_t + (size_t)b * N_SPA * C_DIM;
    const short* kb = k_t + (size_t)b * N_SPA * C_DIM;
    const short* vb = v_ + (size_t)b * N_SPA;      // [C] rows, stride NALL
    short* ob = o_t + (size_t)b * N_SPA * C_DIM;   // overwrites h_t[b] (dead)
    // logits[i][j] = scale * sum_c q_t[i][c] k_t[j][c]
    gemm_bt<2><<<gattn, 256, 0, stream>>>(qb, kb, p, nullptr, nullptr,
                                          N_SPA, N_SPA, C_DIM, C_DIM, C_DIM, N_SPA, scale);
    softmax_kernel<<<N_SPA, 256, 0, stream>>>(p);
    // part[s][i][c] = sum_{j in split s} p[i][j] v[c][b*N+j]
    gemm_bt<5><<<gpv, 256, 0, stream>>>(p, vb, part, nullptr, nullptr,
                                        N_SPA, C_DIM, N_SPA / 4, N_SPA, NALL, C_DIM, 0.f);
    pv_reduce<<<2048, 256, 0, stream>>>(part, ob);
  }
  // y[b][c][n] = x + bo[c] + sum_k Wo[c][k] o_t[b*N+n][k]
  gemm_bt<4><<<gproj, 256, 0, stream>>>(Wb + 3 * 262144, o_t, out, bo, x,
                                        C_DIM, NALL, C_DIM, C_DIM, C_DIM, 0, 0.f);
}

// Round 6
// 421.852 us; speedup vs baseline: 2.3183x; 1.2402x over previous
//
#include <hip/hip_runtime.h>
#include <hip/hip_bf16.h>

// AudioAttnBlock: GroupNorm -> QKV 1x1 conv -> spatial attention -> out proj -> residual
// B=4, C=512, N=4096 (64x64), 32 groups. bf16 MFMA 16x16x32, fp32 accumulate.
// R6: identical to R5 design; fixes the comment-backslash line-continuation that
//     swallowed the k_t declaration (compile error).

#define C_DIM 512
#define N_SPA 4096
#define BATCH 4
#define NALL 16384  // BATCH * N_SPA

#define BM 128
#define BN 128
#define BK 32

typedef short short8 __attribute__((ext_vector_type(8)));
typedef short short4v __attribute__((ext_vector_type(4)));
typedef float float4v __attribute__((ext_vector_type(4)));

__device__ __forceinline__ short f2b(float f) {
  __hip_bfloat16 h = __float2bfloat16(f);
  return *reinterpret_cast<short*>(&h);
}
__device__ __forceinline__ float b2f(short s) {
  __hip_bfloat16 h;
  *reinterpret_cast<short*>(&h) = s;
  return __bfloat162float(h);
}

typedef __attribute__((address_space(1))) const void gvoid_t;
typedef __attribute__((address_space(3))) void lvoid_t;
__device__ __forceinline__ void gload16(const void* g, void* l) {
  __builtin_amdgcn_global_load_lds((gvoid_t*)g, (lvoid_t*)l, 16, 0, 0);
}

// ---------------- weights fp32 -> bf16, biases concat ----------------
__global__ void wconv_kernel(const float* __restrict__ Wq, const float* __restrict__ Wk,
                             const float* __restrict__ Wv, const float* __restrict__ Wo,
                             const float* __restrict__ bq, const float* __restrict__ bk,
                             const float* __restrict__ bv,
                             short* __restrict__ out, float* __restrict__ bias_all) {
  int i = blockIdx.x * 256 + threadIdx.x;
  out[0 * 262144 + i] = f2b(Wq[i]);
  out[1 * 262144 + i] = f2b(Wk[i]);
  out[2 * 262144 + i] = f2b(Wv[i]);
  out[3 * 262144 + i] = f2b(Wo[i]);
  if (i < 1536) bias_all[i] = (i < 512) ? bq[i] : (i < 1024) ? bk[i - 512] : bv[i - 1024];
}

// ---------------- GroupNorm phase 1: partial sums ----------------
__global__ void gn_part(const float* __restrict__ x, float2* __restrict__ partials) {
  int grp = blockIdx.x >> 5, split = blockIdx.x & 31;
  const float4* xg = (const float4*)(x + (size_t)grp * 65536 + split * 2048);
  int t = threadIdx.x;
  float4 a = xg[t], b4 = xg[256 + t];
  float s = a.x + a.y + a.z + a.w + b4.x + b4.y + b4.z + b4.w;
  float ss = a.x * a.x + a.y * a.y + a.z * a.z + a.w * a.w +
             b4.x * b4.x + b4.y * b4.y + b4.z * b4.z + b4.w * b4.w;
  __shared__ float red[512];
  red[t] = s; red[256 + t] = ss;
  __syncthreads();
  for (int off = 128; off > 0; off >>= 1) {
    if (t < off) { red[t] += red[t + off]; red[256 + t] += red[256 + t + off]; }
    __syncthreads();
  }
  if (t == 0) partials[blockIdx.x] = make_float2(red[0], red[256]);
}

// ---------------- GroupNorm phase 2: normalize + transpose ----------------
__global__ void gn_norm(const float* __restrict__ x, const float* __restrict__ gamma,
                        const float* __restrict__ beta, const float2* __restrict__ partials,
                        short* __restrict__ h_t) {
  int bid = blockIdx.x;
  int grp = bid >> 4, seg = bid & 15;
  int b = grp >> 5, g = grp & 31;
  float s = 0.f, ss = 0.f;
  for (int j = 0; j < 32; ++j) { float2 p2 = partials[grp * 32 + j]; s += p2.x; ss += p2.y; }
  float mean = s * (1.0f / 65536.0f);
  float rstd = rsqrtf(ss * (1.0f / 65536.0f) - mean * mean + 1e-6f);

  const float* xg = x + (size_t)grp * 65536 + seg * 256;
  __shared__ float tile[16][257];
  int t = threadIdx.x;
#pragma unroll
  for (int i = 0; i < 16; ++i) tile[i][t] = xg[(size_t)i * N_SPA + t];
  __syncthreads();

  int c8 = (t & 1) * 8, ci = g * 16 + c8;
  float ga[8], be[8];
#pragma unroll
  for (int j = 0; j < 8; ++j) { ga[j] = gamma[ci + j]; be[j] = beta[ci + j]; }
#pragma unroll
  for (int pass = 0; pass < 2; ++pass) {
    int nl = (t >> 1) + pass * 128;
    short8 o;
#pragma unroll
    for (int j = 0; j < 8; ++j) {
      float v = (tile[c8 + j][nl] - mean) * rstd * ga[j] + be[j];
      o[j] = f2b(v);
    }
    *(short8*)&h_t[((size_t)b * N_SPA + seg * 256 + nl) * C_DIM + ci] = o;
  }
}

// ---------------- GEMM: C[M,N] = A[M,K] * BT[N,K]^T, z-batched ----------------
// A += z*az, BT += z*bz, out += z*cz (elements).
// EPI 2: bf16 out [m][n], *scale                     (attn logits)
// EPI 3: bf16 out transposed [n][m]                  (o_t = (V P^T)^T)
// EPI 4: fp32 out, +bias[m] +resid, batched [B][C][N] decomposition of nn
// EPI 6: fused QKV: z<2 -> transposed [n][C] +bias; z==2 -> normal [C][NALL] +bias
template <int EPI>
__global__ __launch_bounds__(256) void gemm_bt(
    const short* __restrict__ A, const short* __restrict__ BT, void* __restrict__ Cout,
    const float* __restrict__ bias, const float* __restrict__ resid,
    int M, int N, int K, int lda, int ldb, int ldc,
    size_t az, size_t bz, size_t cz, float scale) {
  __shared__ __align__(16) short lds_a[BM * BK];
  __shared__ __align__(16) short lds_b[BN * BK];
  int t = threadIdx.x;
  int m0 = blockIdx.y * BM;
  int n0 = blockIdx.x * BN;
  int z = blockIdx.z;
  A += (size_t)z * az;
  BT += (size_t)z * bz;
  int w = t >> 6, l = t & 63;
  int wm = (w >> 1) * 64, wn = (w & 1) * 64;
  int lr = l & 15, lk = l >> 4;

  // staging: wave w covers rows w*16..w*16+15 (and +64); lane l -> row w*16+(l>>2), col (l&3)*8
  int sr = l >> 2, scol = (l & 3) * 8;
  const short* ga0 = A + (size_t)(m0 + w * 16 + sr) * lda + scol;
  const short* ga1 = ga0 + (size_t)64 * lda;
  const short* gb0 = BT + (size_t)(n0 + w * 16 + sr) * ldb + scol;
  const short* gb1 = gb0 + (size_t)64 * ldb;
  short* la0 = &lds_a[w * 16 * BK];
  short* la1 = &lds_a[(64 + w * 16) * BK];
  short* lb0 = &lds_b[w * 16 * BK];
  short* lb1 = &lds_b[(64 + w * 16) * BK];

  float4v acc[4][4];
#pragma unroll
  for (int i = 0; i < 4; ++i)
#pragma unroll
    for (int j = 0; j < 4; ++j) acc[i][j] = (float4v){0.f, 0.f, 0.f, 0.f};

  for (int k0 = 0; k0 < K; k0 += BK) {
    __syncthreads();
    gload16(ga0, la0); gload16(ga1, la1);
    gload16(gb0, lb0); gload16(gb1, lb1);
    ga0 += BK; ga1 += BK; gb0 += BK; gb1 += BK;
    __syncthreads();
    short8 af[4], bf[4];
#pragma unroll
    for (int i = 0; i < 4; ++i) af[i] = *(const short8*)&lds_a[(wm + i * 16 + lr) * BK + lk * 8];
#pragma unroll
    for (int i = 0; i < 4; ++i) bf[i] = *(const short8*)&lds_b[(wn + i * 16 + lr) * BK + lk * 8];
#pragma unroll
    for (int i = 0; i < 4; ++i)
#pragma unroll
      for (int j = 0; j < 4; ++j)
        acc[i][j] = __builtin_amdgcn_mfma_f32_16x16x32_bf16(af[i], bf[j], acc[i][j], 0, 0, 0);
  }

#pragma unroll
  for (int i = 0; i < 4; ++i)
#pragma unroll
    for (int j = 0; j < 4; ++j) {
      int mB = m0 + wm + i * 16 + lk * 4;   // first of 4 consecutive out-rows
      int nn = n0 + wn + j * 16 + lr;       // out-column
      if constexpr (EPI == 2) {
        short* outp = (short*)Cout + (size_t)z * cz;
#pragma unroll
        for (int r = 0; r < 4; ++r)
          outp[(size_t)(mB + r) * ldc + nn] = f2b(acc[i][j][r] * scale);
      } else if constexpr (EPI == 3) {
        short* outp = (short*)Cout + (size_t)z * cz;
        short4v v;
#pragma unroll
        for (int r = 0; r < 4; ++r) v[r] = f2b(acc[i][j][r]);
        *(short4v*)(outp + (size_t)nn * ldc + mB) = v;
      } else if constexpr (EPI == 4) {  // y[b][c][n] = acc + bias[c] + x[b][c][n]
        int bb = nn >> 12, n = nn & 4095;
        size_t base = ((size_t)bb * C_DIM + mB) * N_SPA + n;
#pragma unroll
        for (int r = 0; r < 4; ++r) {
          float f = acc[i][j][r] + bias[mB + r] + resid[base + (size_t)r * N_SPA];
          ((float*)Cout)[base + (size_t)r * N_SPA] = f;
        }
      } else {  // EPI 6: fused QKV; q_t,k_t,v_ contiguous after Cout
        short* outp = (short*)Cout + (size_t)z * NALL * C_DIM;
        const float* bz_ = bias + (size_t)z * C_DIM;
        if (z < 2) {  // transposed [n][C]
          short4v v;
#pragma unroll
          for (int r = 0; r < 4; ++r) v[r] = f2b(acc[i][j][r] + bz_[mB + r]);
          *(short4v*)(outp + (size_t)nn * C_DIM + mB) = v;
        } else {      // v: normal [C][NALL]
#pragma unroll
          for (int r = 0; r < 4; ++r)
            outp[(size_t)(mB + r) * NALL + nn] = f2b(acc[i][j][r] + bz_[mB + r]);
        }
      }
    }
}

// ---------------- row softmax over 4096 cols, bf16 in-place, batched ----------------
__global__ void softmax_kernel(short* __restrict__ p) {
  size_t row = blockIdx.x;
  short8* pr = (short8*)(p + row * N_SPA);
  int t = threadIdx.x;
  short8 a = pr[t * 2], b = pr[t * 2 + 1];
  float v[16];
#pragma unroll
  for (int j = 0; j < 8; ++j) { v[j] = b2f(a[j]); v[8 + j] = b2f(b[j]); }
  float mx = v[0];
#pragma unroll
  for (int j = 1; j < 16; ++j) mx = fmaxf(mx, v[j]);
  __shared__ float red[256];
  red[t] = mx; __syncthreads();
  for (int off = 128; off > 0; off >>= 1) {
    if (t < off) red[t] = fmaxf(red[t], red[t + off]);
    __syncthreads();
  }
  mx = red[0];
  __syncthreads();
  float s = 0.f;
#pragma unroll
  for (int j = 0; j < 16; ++j) { v[j] = __expf(v[j] - mx); s += v[j]; }
  red[t] = s; __syncthreads();
  for (int off = 128; off > 0; off >>= 1) {
    if (t < off) red[t] += red[t + off];
    __syncthreads();
  }
  float inv = 1.0f / red[0];
  short8 oa, ob;
#pragma unroll
  for (int j = 0; j < 8; ++j) { oa[j] = f2b(v[j] * inv); ob[j] = f2b(v[8 + j] * inv); }
  pr[t * 2] = oa; pr[t * 2 + 1] = ob;
}

extern "C" void kernel_launch(void* const* d_in, const int* in_sizes, int n_in,
                              void* d_out, int out_size, void* d_ws, size_t ws_size,
                              hipStream_t stream) {
  const float* x     = (const float*)d_in[0];
  const float* gamma = (const float*)d_in[1];
  const float* beta  = (const float*)d_in[2];
  const float* Wq = (const float*)d_in[3];  const float* bq = (const float*)d_in[4];
  const float* Wk = (const float*)d_in[5];  const float* bk = (const float*)d_in[6];
  const float* Wv = (const float*)d_in[7];  const float* bv = (const float*)d_in[8];
  const float* Wo = (const float*)d_in[9];  const float* bo = (const float*)d_in[10];
  float* out = (float*)d_out;

  // workspace carve (shorts). Wb 2MiB; h_t/q_t/k_t/v_ 16MiB each; p 128MiB. ~194MiB of 256.
  // q_t, k_t, v_ must stay contiguous in this order (EPI6 indexes z*NALL*C_DIM).
  short* Wb  = (short*)d_ws;
  short* h_t = Wb + 4 * 262144;
  short* q_t = h_t + (size_t)NALL * C_DIM;
  short* k_t = q_t + (size_t)NALL * C_DIM;
  short* v_  = k_t + (size_t)NALL * C_DIM;
  short* p   = v_  + (size_t)NALL * C_DIM;
  float2* partials = (float2*)(p + (size_t)BATCH * N_SPA * N_SPA);  // 4096 float2
  float* bias_all = (float*)(partials + 4096);                      // 1536 floats
  short* o_t = h_t;  // h_t dead after QKV; reused as o_t

  wconv_kernel<<<1024, 256, 0, stream>>>(Wq, Wk, Wv, Wo, bq, bk, bv, Wb, bias_all);
  gn_part<<<BATCH * 32 * 32, 256, 0, stream>>>(x, partials);
  gn_norm<<<BATCH * 32 * 16, 256, 0, stream>>>(x, gamma, beta, partials, h_t);

  const float scale = 0.04419417382415922f;  // 512^-0.5
  const size_t pz = (size_t)N_SPA * N_SPA;   // per-batch p stride
  const size_t hz = (size_t)N_SPA * C_DIM;   // per-batch row-major stride

  // fused QKV: z in {0:q_t,1:k_t,2:v_}, 1536 blocks
  gemm_bt<6><<<dim3(NALL / BN, C_DIM / BM, 3), 256, 0, stream>>>(
      Wb, h_t, q_t, bias_all, nullptr,
      C_DIM, NALL, C_DIM, C_DIM, C_DIM, C_DIM, 262144, 0, 0, 0.f);

  // batched logits: p[b][i][j] = scale * sum_c q_t[b*N+i][c] k_t[b*N+j][c], 4096 blocks
  gemm_bt<2><<<dim3(N_SPA / BN, N_SPA / BM, BATCH), 256, 0, stream>>>(
      q_t, k_t, p, nullptr, nullptr,
      N_SPA, N_SPA, C_DIM, C_DIM, C_DIM, N_SPA, hz, hz, pz, scale);

  softmax_kernel<<<BATCH * N_SPA, 256, 0, stream>>>(p);

  // batched PV: o_t[b*N+i][c] = sum_j v[c][b*N+j] p[b][i][j], 512 blocks
  gemm_bt<3><<<dim3(N_SPA / BN, C_DIM / BM, BATCH), 256, 0, stream>>>(
      v_, p, o_t, nullptr, nullptr,
      C_DIM, N_SPA, N_SPA, NALL, N_SPA, C_DIM, N_SPA, pz, hz, 0.f);

  // final: y[b][c][n] = x + bo[c] + sum_k Wo[c][k] o_t[b*N+n][k], 512 blocks
  gemm_bt<4><<<dim3(NALL / BN, C_DIM / BM, 1), 256, 0, stream>>>(
      Wb + 3 * 262144, o_t, out, bo, x,
      C_DIM, NALL, C_DIM, C_DIM, C_DIM, 0, 0, 0, 0, 0.f);
}